// Round 6
// baseline (1063.067 us; speedup 1.0000x reference)
//
#include <hip/hip_runtime.h>
#include <hip/hip_bf16.h>

typedef __hip_bfloat16 bf16;

// ---- adaptive loads: fb=1 -> bf16 data, fb=0 -> float32 data ----
__device__ __forceinline__ float ldf(const void* p, int fb, size_t i) {
    if (fb) {
        unsigned int u = ((const unsigned short*)p)[i];
        return __uint_as_float(u << 16);
    }
    return ((const float*)p)[i];
}
// fi=1 -> int64 underlying (read low word), fi=0 -> int32. Clamped to [0,n).
__device__ __forceinline__ int ldi(const int* p, int fi, size_t i, int n) {
    int v = fi ? p[2 * i] : p[i];
    return ((unsigned)v < (unsigned)n) ? v : 0;
}
__device__ __forceinline__ float bf2f_bits(unsigned short u) {
    return __uint_as_float(((unsigned int)u) << 16);
}

// ---------------- dtype detection ----------------
__global__ void k_detect(const void* x, const int* ei, int* flags) {
    if (threadIdx.x == 0 && blockIdx.x == 0) {
        const unsigned short* u = (const unsigned short*)x;
        int bad = 0;
        for (int i = 0; i < 128; ++i) {
            float v = bf2f_bits(u[i]);
            if (!(v > -64.f && v < 64.f)) bad++;  // NaN fails both
        }
        flags[0] = (bad >= 4) ? 0 : 1;  // 1 = floats are bf16
        int nz = 0;
        for (int i = 0; i < 64; ++i) nz |= ei[2 * i + 1];
        flags[1] = (nz == 0) ? 1 : 0;   // 1 = indices are int64
    }
}

__global__ void k_sentinel(float* out, int nfloats) {
    int i = blockIdx.x * blockDim.x + threadIdx.x;
    if (i < nfloats) out[i] = 1000.0f;
}

// ---------------- CSR build ----------------
__global__ void k_zero(int* counts, int n1) {
    int i = blockIdx.x * blockDim.x + threadIdx.x;
    if (i < n1) counts[i] = 0;
}

__global__ void k_hist(const int* __restrict__ ei, const int* __restrict__ flags,
                       int* counts, int E, int n) {
    int e = blockIdx.x * blockDim.x + threadIdx.x;
    if (e >= E) return;
    int c = ldi(ei, flags[1], (size_t)E + e, n);
    atomicAdd(&counts[c], 1);
}

__global__ void k_dinv(const int* __restrict__ counts, float* __restrict__ dinv, int n) {
    int i = blockIdx.x * blockDim.x + threadIdx.x;
    if (i < n) dinv[i] = rsqrtf((float)(counts[i] + 1));  // +1 self loop
}

// chunk = 512. scan1: per-chunk exclusive scan into rowptr, chunk total to chsum.
__global__ void k_scan1(const int* __restrict__ counts, int* __restrict__ rowptr,
                        int* __restrict__ chsum, int n) {
    __shared__ int s[512];
    int t = threadIdx.x, i = blockIdx.x * 512 + t;
    int v = (i < n) ? counts[i] : 0;
    s[t] = v;
    __syncthreads();
    for (int off = 1; off < 512; off <<= 1) {
        int add = (t >= off) ? s[t - off] : 0;
        __syncthreads();
        s[t] += add;
        __syncthreads();
    }
    if (i < n) rowptr[i] = s[t] - v;            // chunk-local exclusive
    if (t == 511) chsum[blockIdx.x] = s[511];   // chunk total
}

// scan2: one block scans <=256 chunk sums (exclusive, in place)
__global__ void k_scan2(int* chsum, int nch) {
    __shared__ int s[256];
    int t = threadIdx.x;
    int v = (t < nch) ? chsum[t] : 0;
    s[t] = v;
    __syncthreads();
    for (int off = 1; off < 256; off <<= 1) {
        int add = (t >= off) ? s[t - off] : 0;
        __syncthreads();
        s[t] += add;
        __syncthreads();
    }
    if (t < nch) chsum[t] = s[t] - v;           // exclusive
}

// scan3: add chunk offsets; write cursor copy into counts; rowptr[n]=E
__global__ void k_scan3(int* __restrict__ rowptr, const int* __restrict__ chsum,
                        int* __restrict__ counts, int n, int E) {
    int t = threadIdx.x, i = blockIdx.x * 512 + t;
    if (i < n) {
        int val = rowptr[i] + chsum[blockIdx.x];
        rowptr[i] = val;
        counts[i] = val;  // cursor
    }
    if (blockIdx.x == 0 && t == 0) rowptr[n] = E;
}

__global__ void k_fill(const int* __restrict__ ei, const int* __restrict__ flags,
                       int* __restrict__ cursor, int* __restrict__ srcs, int E, int n) {
    int e = blockIdx.x * blockDim.x + threadIdx.x;
    if (e >= E) return;
    int fi = flags[1];
    int r = ldi(ei, fi, e, n);
    int c = ldi(ei, fi, (size_t)E + e, n);
    int pos = atomicAdd(&cursor[c], 1);
    srcs[pos] = r;
}

// ---------------- layer-1 aggregation (gather): aggx[i] = dinv_i*(sum + dinv_i*x_i)
__global__ void k_gather_x(const void* __restrict__ x, const int* __restrict__ flags,
                           const float* __restrict__ dinv, const int* __restrict__ rowptr,
                           const int* __restrict__ srcs, float* __restrict__ aggx, int n) {
    int i = blockIdx.x * blockDim.x + threadIdx.x;
    if (i >= n) return;
    int fb = flags[0];
    float di = dinv[i];
    float a0 = di * ldf(x, fb, 2 * (size_t)i);
    float a1 = di * ldf(x, fb, 2 * (size_t)i + 1);
    int mend = rowptr[i + 1];
    for (int m = rowptr[i]; m < mend; ++m) {
        int r = srcs[m];
        float dr = dinv[r];
        a0 += dr * ldf(x, fb, 2 * (size_t)r);
        a1 += dr * ldf(x, fb, 2 * (size_t)r + 1);
    }
    aggx[2 * i]     = di * a0;
    aggx[2 * i + 1] = di * a1;
}

// h1 = relu(aggx@W1+b1) on the fly, xw2 = h1@W2 (bf16). grid-stride, 32 thr/node.
__global__ void k_h1_xw2(const float* __restrict__ aggx, const int* __restrict__ flags,
                         const void* __restrict__ W1, const void* __restrict__ b1,
                         const void* __restrict__ W2,
                         unsigned short* __restrict__ xw2, int n) {
    __shared__ float sW1[128];
    __shared__ float sb1[64];
    __shared__ float sW2[64 * 32];
    int tid = threadIdx.x;
    int fb = flags[0];
    for (int idx = tid; idx < 128; idx += blockDim.x) sW1[idx] = ldf(W1, fb, idx);
    for (int idx = tid; idx < 64; idx += blockDim.x)  sb1[idx] = ldf(b1, fb, idx);
    for (int idx = tid; idx < 64 * 32; idx += blockDim.x) sW2[idx] = ldf(W2, fb, idx);
    __syncthreads();
    int total = n * 32;
    int stride = gridDim.x * blockDim.x;
    for (int t = blockIdx.x * blockDim.x + tid; t < total; t += stride) {
        int i = t >> 5, j = t & 31;
        float a0 = aggx[2 * i], a1 = aggx[2 * i + 1];
        float s = 0.f;
#pragma unroll
        for (int k = 0; k < 64; ++k) {
            float h = fmaxf(a0 * sW1[k] + a1 * sW1[64 + k] + sb1[k], 0.f);
            s += h * sW2[k * 32 + j];
        }
        xw2[t] = (unsigned short)(__float_as_uint(s) >> 16);
    }
}

// layer-2 aggregation (gather): 32 lanes per node, zero atomics.
// h2[i,k] = relu(dinv_i*(sum_r dinv_r*xw2[r,k] + dinv_i*xw2[i,k]) + b2[k])
__global__ void k_gather2(const unsigned short* __restrict__ xw2, const int* __restrict__ flags,
                          const float* __restrict__ dinv, const int* __restrict__ rowptr,
                          const int* __restrict__ srcs, const void* __restrict__ b2v,
                          unsigned short* __restrict__ h2, int n) {
    int t = blockIdx.x * blockDim.x + threadIdx.x;
    int i = t >> 5, k = t & 31;
    if (i >= n) return;
    float di = dinv[i];
    float acc = di * bf2f_bits(xw2[(size_t)i * 32 + k]);
    int mend = rowptr[i + 1];
    for (int m = rowptr[i]; m < mend; ++m) {
        int r = srcs[m];
        acc += dinv[r] * bf2f_bits(xw2[(size_t)r * 32 + k]);
    }
    float v = fmaxf(di * acc + ldf(b2v, flags[0], k), 0.f);
    h2[t] = (unsigned short)(__float_as_uint(v) >> 16);
}

// ---------------- edge MLP: 16 lanes/edge, grid-stride, direct h2 loads ----------------
// Round-5 was LDS-pipe-bound: 36 bpermutes/edge-lane + 17 ds_read_b128 weight loads
// per edge. Now: weights in named regs ONCE per thread (grid-stride amortizes), h2
// rows loaded directly as uint4 (L1 broadcasts the shared 64B line within a group).
#define ACC8(A, WA, WB)                                                              \
    accj += __uint_as_float((A).x << 16) * (WA).x                                    \
          + __uint_as_float((A).x & 0xffff0000u) * (WA).y                            \
          + __uint_as_float((A).y << 16) * (WA).z                                    \
          + __uint_as_float((A).y & 0xffff0000u) * (WA).w                            \
          + __uint_as_float((A).z << 16) * (WB).x                                    \
          + __uint_as_float((A).z & 0xffff0000u) * (WB).y                            \
          + __uint_as_float((A).w << 16) * (WB).z                                    \
          + __uint_as_float((A).w & 0xffff0000u) * (WB).w;

__global__ void k_edge_mlp(const int* __restrict__ ei, const int* __restrict__ flags,
                           const unsigned short* __restrict__ h2, const void* __restrict__ ea,
                           const void* __restrict__ Wm1, const void* __restrict__ bm1,
                           const void* __restrict__ Wm2, const void* __restrict__ bm2,
                           void* __restrict__ out, int E, int n) {
    // sWt: Wm1 transposed, column-major: sWt[j*68 + row] = Wm1[row][j]
    __shared__ __align__(16) float sWt[16 * 68];
    __shared__ float sB[16];
    __shared__ float sW2v[16];
    __shared__ float sB2;
    int tid = threadIdx.x;
    int fb = flags[0], fi = flags[1];
    for (int idx = tid; idx < 66 * 16; idx += blockDim.x) {
        int rrow = idx >> 4, jj = idx & 15;
        sWt[jj * 68 + rrow] = ldf(Wm1, fb, idx);
    }
    if (tid < 16) sB[tid] = ldf(bm1, fb, tid);
    else if (tid < 32) sW2v[tid - 16] = ldf(Wm2, fb, tid - 16);
    else if (tid == 32) sB2 = ldf(bm2, fb, 0);
    __syncthreads();

    int j = tid & 15;
    // per-lane weights: column j of Wm1, rows 0..65 (loaded ONCE per thread)
    const float* wc = sWt + j * 68;
    float4 w0 = *(const float4*)(wc +  0), w1 = *(const float4*)(wc +  4);
    float4 w2 = *(const float4*)(wc +  8), w3 = *(const float4*)(wc + 12);
    float4 w4 = *(const float4*)(wc + 16), w5 = *(const float4*)(wc + 20);
    float4 w6 = *(const float4*)(wc + 24), w7 = *(const float4*)(wc + 28);
    float4 w8  = *(const float4*)(wc + 32), w9  = *(const float4*)(wc + 36);
    float4 w10 = *(const float4*)(wc + 40), w11 = *(const float4*)(wc + 44);
    float4 w12 = *(const float4*)(wc + 48), w13 = *(const float4*)(wc + 52);
    float4 w14 = *(const float4*)(wc + 56), w15 = *(const float4*)(wc + 60);
    float wea0 = wc[64], wea1 = wc[65];
    float bj = sB[j], w2j = sW2v[j], b2s = sB2;

    const uint4* h2u4 = (const uint4*)h2;
    int gid = (blockIdx.x * blockDim.x + tid) >> 4;
    int ngroups = (gridDim.x * blockDim.x) >> 4;

    for (int e = gid; e < E; e += ngroups) {
        int r = ldi(ei, fi, e, n);
        int c = ldi(ei, fi, (size_t)E + e, n);
        float accj = bj;
        {
            const uint4* hr = h2u4 + (size_t)r * 4;
            uint4 a0 = hr[0], a1 = hr[1], a2 = hr[2], a3 = hr[3];
            ACC8(a0, w0, w1) ACC8(a1, w2, w3) ACC8(a2, w4, w5) ACC8(a3, w6, w7)
        }
        {
            const uint4* hc = h2u4 + (size_t)c * 4;
            uint4 a0 = hc[0], a1 = hc[1], a2 = hc[2], a3 = hc[3];
            ACC8(a0, w8, w9) ACC8(a1, w10, w11) ACC8(a2, w12, w13) ACC8(a3, w14, w15)
        }
        accj += ldf(ea, fb, 2 * (size_t)e) * wea0 + ldf(ea, fb, 2 * (size_t)e + 1) * wea1;

        float pj = fmaxf(accj, 0.f) * w2j;
        pj += __shfl_xor(pj, 8, 16);
        pj += __shfl_xor(pj, 4, 16);
        pj += __shfl_xor(pj, 2, 16);
        pj += __shfl_xor(pj, 1, 16);
        if (j == 0) {
            float o = pj + b2s;
            if (fb) ((bf16*)out)[e] = __float2bfloat16(o);
            else    ((float*)out)[e] = o;
        }
    }
}
#undef ACC8

extern "C" void kernel_launch(void* const* d_in, const int* in_sizes, int n_in,
                              void* d_out, int out_size, void* d_ws, size_t ws_size,
                              hipStream_t stream) {
    const void* x   = d_in[0];
    const int*  ei  = (const int*)d_in[1];
    const void* ea  = d_in[2];
    const void* W1  = d_in[3];
    const void* b1  = d_in[4];
    const void* W2  = d_in[5];
    const void* b2  = d_in[6];
    const void* Wm1 = d_in[7];
    const void* bm1 = d_in[8];
    const void* Wm2 = d_in[9];
    const void* bm2 = d_in[10];

    int n = in_sizes[0] / 2;   // x is [N,2]
    int E = in_sizes[2] / 2;   // edge_attr is [E,2]

    // workspace carve-out (~21.2 MB)
    char* ws = (char*)d_ws;
    size_t off = 0;
    auto take = [&](size_t bytes) -> char* {
        char* p = ws + off;
        off += bytes;
        off = (off + 255) & ~(size_t)255;
        return p;
    };
    int* flags   = (int*)take(8);
    int* counts  = (int*)take((size_t)(n + 1) * 4);   // hist -> cursor
    float* dinv  = (float*)take((size_t)n * 4);
    int* rowptr  = (int*)take((size_t)(n + 1) * 4);
    int* chsum   = (int*)take(1024);
    int* srcs    = (int*)take((size_t)E * 4);
    float* aggx  = (float*)take((size_t)n * 2 * 4);
    unsigned short* xw2 = (unsigned short*)take((size_t)n * 32 * 2);
    unsigned short* h2  = (unsigned short*)take((size_t)n * 32 * 2);

    if (off > ws_size) {
        int nf = out_size / 2;
        if (nf > 0) k_sentinel<<<(nf + 255) / 256, 256, 0, stream>>>((float*)d_out, nf);
        return;
    }

    const int B = 256;
    int nch = (n + 511) / 512;  // 196 <= 256
    k_detect<<<1, 64, 0, stream>>>(x, ei, flags);
    k_zero<<<(n + 1 + B - 1) / B, B, 0, stream>>>(counts, n + 1);
    k_hist<<<(E + B - 1) / B, B, 0, stream>>>(ei, flags, counts, E, n);
    k_dinv<<<(n + B - 1) / B, B, 0, stream>>>(counts, dinv, n);
    k_scan1<<<nch, 512, 0, stream>>>(counts, rowptr, chsum, n);
    k_scan2<<<1, 256, 0, stream>>>(chsum, nch);
    k_scan3<<<nch, 512, 0, stream>>>(rowptr, chsum, counts, n, E);
    k_fill<<<(E + B - 1) / B, B, 0, stream>>>(ei, flags, counts, srcs, E, n);
    k_gather_x<<<(n + B - 1) / B, B, 0, stream>>>(x, flags, dinv, rowptr, srcs, aggx, n);
    k_h1_xw2<<<1024, B, 0, stream>>>(aggx, flags, W1, b1, W2, xw2, n);
    k_gather2<<<((size_t)n * 32 + B - 1) / B, B, 0, stream>>>(xw2, flags, dinv, rowptr, srcs, b2, h2, n);
    k_edge_mlp<<<2048, B, 0, stream>>>(ei, flags, h2, ea, Wm1, bm1, Wm2, bm2, d_out, E, n);
}

// Round 7
// 578.108 us; speedup vs baseline: 1.8389x; 1.8389x over previous
//
#include <hip/hip_runtime.h>
#include <hip/hip_bf16.h>

typedef __hip_bfloat16 bf16;

// ---- adaptive loads: fb=1 -> bf16 data, fb=0 -> float32 data ----
__device__ __forceinline__ float ldf(const void* p, int fb, size_t i) {
    if (fb) {
        unsigned int u = ((const unsigned short*)p)[i];
        return __uint_as_float(u << 16);
    }
    return ((const float*)p)[i];
}
// fi=1 -> int64 underlying (read low word), fi=0 -> int32. Clamped to [0,n).
__device__ __forceinline__ int ldi(const int* p, int fi, size_t i, int n) {
    int v = fi ? p[2 * i] : p[i];
    return ((unsigned)v < (unsigned)n) ? v : 0;
}
__device__ __forceinline__ float bf2f_bits(unsigned short u) {
    return __uint_as_float(((unsigned int)u) << 16);
}

// ---------------- dtype detection ----------------
__global__ void k_detect(const void* x, const int* ei, int* flags) {
    if (threadIdx.x == 0 && blockIdx.x == 0) {
        const unsigned short* u = (const unsigned short*)x;
        int bad = 0;
        for (int i = 0; i < 128; ++i) {
            float v = bf2f_bits(u[i]);
            if (!(v > -64.f && v < 64.f)) bad++;  // NaN fails both
        }
        flags[0] = (bad >= 4) ? 0 : 1;  // 1 = floats are bf16
        int nz = 0;
        for (int i = 0; i < 64; ++i) nz |= ei[2 * i + 1];
        flags[1] = (nz == 0) ? 1 : 0;   // 1 = indices are int64
    }
}

__global__ void k_sentinel(float* out, int nfloats) {
    int i = blockIdx.x * blockDim.x + threadIdx.x;
    if (i < nfloats) out[i] = 1000.0f;
}

// ---------------- CSR build ----------------
__global__ void k_zero(int* counts, int n1) {
    int i = blockIdx.x * blockDim.x + threadIdx.x;
    if (i < n1) counts[i] = 0;
}

__global__ void k_hist(const int* __restrict__ ei, const int* __restrict__ flags,
                       int* counts, int E, int n) {
    int e = blockIdx.x * blockDim.x + threadIdx.x;
    if (e >= E) return;
    int c = ldi(ei, flags[1], (size_t)E + e, n);
    atomicAdd(&counts[c], 1);
}

__global__ void k_dinv(const int* __restrict__ counts, float* __restrict__ dinv, int n) {
    int i = blockIdx.x * blockDim.x + threadIdx.x;
    if (i < n) dinv[i] = rsqrtf((float)(counts[i] + 1));  // +1 self loop
}

// chunk = 512. scan1: per-chunk exclusive scan into rowptr, chunk total to chsum.
__global__ void k_scan1(const int* __restrict__ counts, int* __restrict__ rowptr,
                        int* __restrict__ chsum, int n) {
    __shared__ int s[512];
    int t = threadIdx.x, i = blockIdx.x * 512 + t;
    int v = (i < n) ? counts[i] : 0;
    s[t] = v;
    __syncthreads();
    for (int off = 1; off < 512; off <<= 1) {
        int add = (t >= off) ? s[t - off] : 0;
        __syncthreads();
        s[t] += add;
        __syncthreads();
    }
    if (i < n) rowptr[i] = s[t] - v;            // chunk-local exclusive
    if (t == 511) chsum[blockIdx.x] = s[511];   // chunk total
}

// scan2: one block scans <=256 chunk sums (exclusive, in place)
__global__ void k_scan2(int* chsum, int nch) {
    __shared__ int s[256];
    int t = threadIdx.x;
    int v = (t < nch) ? chsum[t] : 0;
    s[t] = v;
    __syncthreads();
    for (int off = 1; off < 256; off <<= 1) {
        int add = (t >= off) ? s[t - off] : 0;
        __syncthreads();
        s[t] += add;
        __syncthreads();
    }
    if (t < nch) chsum[t] = s[t] - v;           // exclusive
}

// scan3: add chunk offsets; write cursor copy into counts; rowptr[n]=E
__global__ void k_scan3(int* __restrict__ rowptr, const int* __restrict__ chsum,
                        int* __restrict__ counts, int n, int E) {
    int t = threadIdx.x, i = blockIdx.x * 512 + t;
    if (i < n) {
        int val = rowptr[i] + chsum[blockIdx.x];
        rowptr[i] = val;
        counts[i] = val;  // cursor
    }
    if (blockIdx.x == 0 && t == 0) rowptr[n] = E;
}

__global__ void k_fill(const int* __restrict__ ei, const int* __restrict__ flags,
                       int* __restrict__ cursor, int* __restrict__ srcs, int E, int n) {
    int e = blockIdx.x * blockDim.x + threadIdx.x;
    if (e >= E) return;
    int fi = flags[1];
    int r = ldi(ei, fi, e, n);
    int c = ldi(ei, fi, (size_t)E + e, n);
    int pos = atomicAdd(&cursor[c], 1);
    srcs[pos] = r;
}

// ---------------- layer-1 aggregation (gather): aggx[i] = dinv_i*(sum + dinv_i*x_i)
__global__ void k_gather_x(const void* __restrict__ x, const int* __restrict__ flags,
                           const float* __restrict__ dinv, const int* __restrict__ rowptr,
                           const int* __restrict__ srcs, float* __restrict__ aggx, int n) {
    int i = blockIdx.x * blockDim.x + threadIdx.x;
    if (i >= n) return;
    int fb = flags[0];
    float di = dinv[i];
    float a0 = di * ldf(x, fb, 2 * (size_t)i);
    float a1 = di * ldf(x, fb, 2 * (size_t)i + 1);
    int mend = rowptr[i + 1];
    for (int m = rowptr[i]; m < mend; ++m) {
        int r = srcs[m];
        float dr = dinv[r];
        a0 += dr * ldf(x, fb, 2 * (size_t)r);
        a1 += dr * ldf(x, fb, 2 * (size_t)r + 1);
    }
    aggx[2 * i]     = di * a0;
    aggx[2 * i + 1] = di * a1;
}

// h1 = relu(aggx@W1+b1) on the fly, xw2 = h1@W2 (bf16). One-shot, 32 thr/node.
// Round-6 grid-stride + full unroll spilled ~5.3 KB/thread to scratch
// (FETCH 973 MB, WRITE 417 MB, 512 us). One-shot + unroll-4 caps live ranges.
__global__ void k_h1_xw2(const float* __restrict__ aggx, const int* __restrict__ flags,
                         const void* __restrict__ W1, const void* __restrict__ b1,
                         const void* __restrict__ W2,
                         unsigned short* __restrict__ xw2, int n) {
    __shared__ float sW1[128];
    __shared__ float sb1[64];
    __shared__ float sW2[64 * 32];
    int tid = threadIdx.x;
    int fb = flags[0];
    for (int idx = tid; idx < 128; idx += blockDim.x) sW1[idx] = ldf(W1, fb, idx);
    for (int idx = tid; idx < 64; idx += blockDim.x)  sb1[idx] = ldf(b1, fb, idx);
    for (int idx = tid; idx < 64 * 32; idx += blockDim.x) sW2[idx] = ldf(W2, fb, idx);
    __syncthreads();
    int t = blockIdx.x * blockDim.x + tid;
    if (t >= n * 32) return;
    int i = t >> 5, j = t & 31;
    float a0 = aggx[2 * i], a1 = aggx[2 * i + 1];
    float s = 0.f;
#pragma unroll 4
    for (int k = 0; k < 64; ++k) {
        float h = fmaxf(fmaf(a0, sW1[k], fmaf(a1, sW1[64 + k], sb1[k])), 0.f);
        s = fmaf(h, sW2[k * 32 + j], s);
    }
    xw2[t] = (unsigned short)(__float_as_uint(s) >> 16);
}

// layer-2 aggregation (gather): 32 lanes per node, zero atomics.
// h2[i,k] = relu(dinv_i*(sum_r dinv_r*xw2[r,k] + dinv_i*xw2[i,k]) + b2[k])
__global__ void k_gather2(const unsigned short* __restrict__ xw2, const int* __restrict__ flags,
                          const float* __restrict__ dinv, const int* __restrict__ rowptr,
                          const int* __restrict__ srcs, const void* __restrict__ b2v,
                          unsigned short* __restrict__ h2, int n) {
    int t = blockIdx.x * blockDim.x + threadIdx.x;
    int i = t >> 5, k = t & 31;
    if (i >= n) return;
    float di = dinv[i];
    float acc = di * bf2f_bits(xw2[(size_t)i * 32 + k]);
    int mend = rowptr[i + 1];
    for (int m = rowptr[i]; m < mend; ++m) {
        int r = srcs[m];
        acc += dinv[r] * bf2f_bits(xw2[(size_t)r * 32 + k]);
    }
    float v = fmaxf(di * acc + ldf(b2v, flags[0], k), 0.f);
    h2[t] = (unsigned short)(__float_as_uint(v) >> 16);
}

// ---------------- edge MLP: 16 lanes/edge, grid-stride, direct h2 loads ----------------
#define ACC8(A, WA, WB)                                                              \
    accj += __uint_as_float((A).x << 16) * (WA).x                                    \
          + __uint_as_float((A).x & 0xffff0000u) * (WA).y                            \
          + __uint_as_float((A).y << 16) * (WA).z                                    \
          + __uint_as_float((A).y & 0xffff0000u) * (WA).w                            \
          + __uint_as_float((A).z << 16) * (WB).x                                    \
          + __uint_as_float((A).z & 0xffff0000u) * (WB).y                            \
          + __uint_as_float((A).w << 16) * (WB).z                                    \
          + __uint_as_float((A).w & 0xffff0000u) * (WB).w;

__global__ void k_edge_mlp(const int* __restrict__ ei, const int* __restrict__ flags,
                           const unsigned short* __restrict__ h2, const void* __restrict__ ea,
                           const void* __restrict__ Wm1, const void* __restrict__ bm1,
                           const void* __restrict__ Wm2, const void* __restrict__ bm2,
                           void* __restrict__ out, int E, int n) {
    // sWt: Wm1 transposed, column-major: sWt[j*68 + row] = Wm1[row][j]
    __shared__ __align__(16) float sWt[16 * 68];
    __shared__ float sB[16];
    __shared__ float sW2v[16];
    __shared__ float sB2;
    int tid = threadIdx.x;
    int fb = flags[0], fi = flags[1];
    for (int idx = tid; idx < 66 * 16; idx += blockDim.x) {
        int rrow = idx >> 4, jj = idx & 15;
        sWt[jj * 68 + rrow] = ldf(Wm1, fb, idx);
    }
    if (tid < 16) sB[tid] = ldf(bm1, fb, tid);
    else if (tid < 32) sW2v[tid - 16] = ldf(Wm2, fb, tid - 16);
    else if (tid == 32) sB2 = ldf(bm2, fb, 0);
    __syncthreads();

    int j = tid & 15;
    // per-lane weights: column j of Wm1, rows 0..65 (loaded ONCE per thread)
    const float* wc = sWt + j * 68;
    float4 w0 = *(const float4*)(wc +  0), w1 = *(const float4*)(wc +  4);
    float4 w2 = *(const float4*)(wc +  8), w3 = *(const float4*)(wc + 12);
    float4 w4 = *(const float4*)(wc + 16), w5 = *(const float4*)(wc + 20);
    float4 w6 = *(const float4*)(wc + 24), w7 = *(const float4*)(wc + 28);
    float4 w8  = *(const float4*)(wc + 32), w9  = *(const float4*)(wc + 36);
    float4 w10 = *(const float4*)(wc + 40), w11 = *(const float4*)(wc + 44);
    float4 w12 = *(const float4*)(wc + 48), w13 = *(const float4*)(wc + 52);
    float4 w14 = *(const float4*)(wc + 56), w15 = *(const float4*)(wc + 60);
    float wea0 = wc[64], wea1 = wc[65];
    float bj = sB[j], w2j = sW2v[j], b2s = sB2;

    const uint4* h2u4 = (const uint4*)h2;
    int gid = (blockIdx.x * blockDim.x + tid) >> 4;
    int ngroups = (gridDim.x * blockDim.x) >> 4;

    for (int e = gid; e < E; e += ngroups) {
        int r = ldi(ei, fi, e, n);
        int c = ldi(ei, fi, (size_t)E + e, n);
        float accj = bj;
        {
            const uint4* hr = h2u4 + (size_t)r * 4;
            uint4 a0 = hr[0], a1 = hr[1], a2 = hr[2], a3 = hr[3];
            ACC8(a0, w0, w1) ACC8(a1, w2, w3) ACC8(a2, w4, w5) ACC8(a3, w6, w7)
        }
        {
            const uint4* hc = h2u4 + (size_t)c * 4;
            uint4 a0 = hc[0], a1 = hc[1], a2 = hc[2], a3 = hc[3];
            ACC8(a0, w8, w9) ACC8(a1, w10, w11) ACC8(a2, w12, w13) ACC8(a3, w14, w15)
        }
        accj += ldf(ea, fb, 2 * (size_t)e) * wea0 + ldf(ea, fb, 2 * (size_t)e + 1) * wea1;

        float pj = fmaxf(accj, 0.f) * w2j;
        pj += __shfl_xor(pj, 8, 16);
        pj += __shfl_xor(pj, 4, 16);
        pj += __shfl_xor(pj, 2, 16);
        pj += __shfl_xor(pj, 1, 16);
        if (j == 0) {
            float o = pj + b2s;
            if (fb) ((bf16*)out)[e] = __float2bfloat16(o);
            else    ((float*)out)[e] = o;
        }
    }
}
#undef ACC8

extern "C" void kernel_launch(void* const* d_in, const int* in_sizes, int n_in,
                              void* d_out, int out_size, void* d_ws, size_t ws_size,
                              hipStream_t stream) {
    const void* x   = d_in[0];
    const int*  ei  = (const int*)d_in[1];
    const void* ea  = d_in[2];
    const void* W1  = d_in[3];
    const void* b1  = d_in[4];
    const void* W2  = d_in[5];
    const void* b2  = d_in[6];
    const void* Wm1 = d_in[7];
    const void* bm1 = d_in[8];
    const void* Wm2 = d_in[9];
    const void* bm2 = d_in[10];

    int n = in_sizes[0] / 2;   // x is [N,2]
    int E = in_sizes[2] / 2;   // edge_attr is [E,2]

    // workspace carve-out (~21.2 MB)
    char* ws = (char*)d_ws;
    size_t off = 0;
    auto take = [&](size_t bytes) -> char* {
        char* p = ws + off;
        off += bytes;
        off = (off + 255) & ~(size_t)255;
        return p;
    };
    int* flags   = (int*)take(8);
    int* counts  = (int*)take((size_t)(n + 1) * 4);   // hist -> cursor
    float* dinv  = (float*)take((size_t)n * 4);
    int* rowptr  = (int*)take((size_t)(n + 1) * 4);
    int* chsum   = (int*)take(1024);
    int* srcs    = (int*)take((size_t)E * 4);
    float* aggx  = (float*)take((size_t)n * 2 * 4);
    unsigned short* xw2 = (unsigned short*)take((size_t)n * 32 * 2);
    unsigned short* h2  = (unsigned short*)take((size_t)n * 32 * 2);

    if (off > ws_size) {
        int nf = out_size / 2;
        if (nf > 0) k_sentinel<<<(nf + 255) / 256, 256, 0, stream>>>((float*)d_out, nf);
        return;
    }

    const int B = 256;
    int nch = (n + 511) / 512;  // 196 <= 256
    k_detect<<<1, 64, 0, stream>>>(x, ei, flags);
    k_zero<<<(n + 1 + B - 1) / B, B, 0, stream>>>(counts, n + 1);
    k_hist<<<(E + B - 1) / B, B, 0, stream>>>(ei, flags, counts, E, n);
    k_dinv<<<(n + B - 1) / B, B, 0, stream>>>(counts, dinv, n);
    k_scan1<<<nch, 512, 0, stream>>>(counts, rowptr, chsum, n);
    k_scan2<<<1, 256, 0, stream>>>(chsum, nch);
    k_scan3<<<nch, 512, 0, stream>>>(rowptr, chsum, counts, n, E);
    k_fill<<<(E + B - 1) / B, B, 0, stream>>>(ei, flags, counts, srcs, E, n);
    k_gather_x<<<(n + B - 1) / B, B, 0, stream>>>(x, flags, dinv, rowptr, srcs, aggx, n);
    k_h1_xw2<<<((size_t)n * 32 + B - 1) / B, B, 0, stream>>>(aggx, flags, W1, b1, W2, xw2, n);
    k_gather2<<<((size_t)n * 32 + B - 1) / B, B, 0, stream>>>(xw2, flags, dinv, rowptr, srcs, b2, h2, n);
    k_edge_mlp<<<2048, B, 0, stream>>>(ei, flags, h2, ea, Wm1, bm1, Wm2, bm2, d_out, E, n);
}